// Round 1
// baseline (12030.591 us; speedup 1.0000x reference)
//
#include <hip/hip_runtime.h>
#include <hip/hip_bf16.h>
#include <stdint.h>

typedef unsigned int uint;
typedef unsigned short ushort;

#define TPB 768

// ---------------- ws layout (ushorts = bf16) ----------------
// A0: W_ih0 packed  768*256   (gi layer0, input = ctl[256])
// A1: W_hh0 packed  768*256   (gh layer0, input = h0[256])
// A2: W_ih1 packed  768*256
// A3: W_hh1 packed  768*256
// A4: W_int packed  320*256
// pack layout for a [ROWS][256] row-major source:
//   ws[base + (kb*ROWS + j)*8 + kl] = bf16( W[j][kb*8+kl] )
// so a uint4 load at (kb*ROWS + j) yields 8 consecutive-k weights of row j.
#define OFF_A0 0
#define OFF_A1 (768*256)
#define OFF_A2 (2*768*256)
#define OFF_A3 (3*768*256)
#define OFF_A4 (4*768*256)
#define WS_USHORTS (4*768*256 + 320*256)   // 868352

__device__ __forceinline__ float bflo(uint u){ return __uint_as_float(u << 16); }
__device__ __forceinline__ float bfhi(uint u){ return __uint_as_float(u & 0xffff0000u); }
__device__ __forceinline__ float sigm(float x){ return 1.0f / (1.0f + __expf(-x)); }
__device__ __forceinline__ float tanh_(float x){
    float xc = fminf(fmaxf(x, -15.0f), 15.0f);
    float e  = __expf(2.0f * xc);
    return (e - 1.0f) / (e + 1.0f);
}

// ---------------- prep: transpose+pack+bf16 all weights into ws ----------------
__global__ void prep_kernel(const float* __restrict__ Wih0, const float* __restrict__ Whh0,
                            const float* __restrict__ Wih1, const float* __restrict__ Whh1,
                            const float* __restrict__ Wint, ushort* __restrict__ ws)
{
    int idx = blockIdx.x * 256 + threadIdx.x;
    if (idx >= WS_USHORTS) return;
    const float* src; int rows; int base; int p;
    if (idx < 4*768*256) {
        int m = idx / (768*256); p = idx % (768*256);
        src  = (m==0) ? Wih0 : (m==1) ? Whh0 : (m==2) ? Wih1 : Whh1;
        rows = 768; base = m * (768*256);
    } else {
        p = idx - 4*768*256; src = Wint; rows = 320; base = 4*768*256;
    }
    int kb  = p / (rows*8);
    int rem = p - kb*(rows*8);
    int j   = rem >> 3;
    int kl  = rem & 7;
    int k   = kb*8 + kl;
    __hip_bfloat16 h = __float2bfloat16(src[j*256 + k]);
    ws[base + p] = *reinterpret_cast<ushort*>(&h);
}

// dual mat-vec: gi[j] = bi[j] + sum_k Wi[j,k]*vin[k];  gh[j] = bh[j] + sum_k Wh[j,k]*hin[k]
// Wi/Wh are packed bf16 (rows=768, CI=256). One output row per thread, LDS-broadcast inputs.
__device__ __forceinline__ void dual_mv(const ushort* __restrict__ Wi, const ushort* __restrict__ Wh,
                                        const float* vin, const float* hin,
                                        const float* __restrict__ bi, const float* __restrict__ bh,
                                        float* go_i, float* go_h, int tid)
{
    int j = tid;
    float ai = bi[j], ah = bh[j];
    const uint4* Pi = (const uint4*)Wi;
    const uint4* Ph = (const uint4*)Wh;
#pragma unroll 4
    for (int kb = 0; kb < 32; ++kb) {
        uint4 wi = Pi[kb*768 + j];
        uint4 wh = Ph[kb*768 + j];
        float4 va = *(const float4*)&vin[kb*8];
        float4 vb = *(const float4*)&vin[kb*8 + 4];
        float4 ha = *(const float4*)&hin[kb*8];
        float4 hb = *(const float4*)&hin[kb*8 + 4];
        ai += bflo(wi.x)*va.x + bfhi(wi.x)*va.y + bflo(wi.y)*va.z + bfhi(wi.y)*va.w
            + bflo(wi.z)*vb.x + bfhi(wi.z)*vb.y + bflo(wi.w)*vb.z + bfhi(wi.w)*vb.w;
        ah += bflo(wh.x)*ha.x + bfhi(wh.x)*ha.y + bflo(wh.y)*ha.z + bfhi(wh.y)*ha.w
            + bflo(wh.z)*hb.x + bfhi(wh.z)*hb.y + bflo(wh.w)*hb.z + bfhi(wh.w)*hb.w;
    }
    go_i[j] = ai; go_h[j] = ah;
}

__global__ __launch_bounds__(TPB) void ebm_main(
    const float* __restrict__ x, const float* __restrict__ h0i,
    const float* __restrict__ b_ih0, const float* __restrict__ b_hh0,
    const float* __restrict__ b_ih1, const float* __restrict__ b_hh1,
    const float* __restrict__ b_int, const float* __restrict__ Wmix,
    const float* __restrict__ bmix,
    const ushort* __restrict__ ws, float* __restrict__ out)
{
    __shared__ float v[256];            // ctl input vector
    __shared__ float gi[768], gh[768];
    __shared__ float h0s[256], h1s[256];
    __shared__ float lread[128];
    __shared__ float em[64][33], bm[64][33];   // +1 pad: kills stride-32 conflicts
    __shared__ float itf[320];
    __shared__ float minv_em[64], minv_bm[64], kinv[8];
    __shared__ float sc[8][64];          // rows 0..3 em, 4..7 bm; scores -> softmax weights
    __shared__ float wwv[64], ev[32], emer[32];
    __shared__ float emrd[4][32], bmrd[4][32];
    __shared__ float wmix_s[32][65];     // +1 pad

    const int tid = threadIdx.x;
    const int b   = blockIdx.x;

    // ---- init state ----
    if (tid < 256) { h0s[tid] = h0i[b*256 + tid]; h1s[tid] = h0i[(64 + b)*256 + tid]; }
    for (int i = tid; i < 64*33; i += TPB) { (&em[0][0])[i] = 0.f; (&bm[0][0])[i] = 0.f; }
    if (tid < 128) lread[tid] = 0.f;
    for (int i = tid; i < 32*64; i += TPB) { wmix_s[i >> 6][i & 63] = Wmix[i]; }
    __syncthreads();

    for (int t = 0; t < 512; ++t) {
        const size_t outbase = ((size_t)b*512 + t) * 640;

        // ---- build ctl = [x_t, l_read] ----
        if (tid < 128)      v[tid] = x[((size_t)b*512 + t)*128 + tid];
        else if (tid < 256) v[tid] = lread[tid - 128];
        __syncthreads();

        // ---- GRU layer 0 mat-vecs ----
        dual_mv(ws + OFF_A0, ws + OFF_A1, v, h0s, b_ih0, b_hh0, gi, gh, tid);
        __syncthreads();
        if (tid < 256) {
            float r  = sigm(gi[tid]       + gh[tid]);
            float z  = sigm(gi[256 + tid] + gh[256 + tid]);
            float n  = tanh_(gi[512 + tid] + r * gh[512 + tid]);
            float hn = (1.f - z) * n + z * h0s[tid];
            h0s[tid] = hn;
            out[outbase + tid] = hn;
        }
        __syncthreads();

        // ---- GRU layer 1 ----
        dual_mv(ws + OFF_A2, ws + OFF_A3, h0s, h1s, b_ih1, b_hh1, gi, gh, tid);
        __syncthreads();
        if (tid < 256) {
            float r  = sigm(gi[tid]       + gh[tid]);
            float z  = sigm(gi[256 + tid] + gh[256 + tid]);
            float n  = tanh_(gi[512 + tid] + r * gh[512 + tid]);
            float hn = (1.f - z) * n + z * h1s[tid];
            h1s[tid] = hn;
            out[outbase + 256 + tid] = hn;
        }
        __syncthreads();

        // ---- interface: itf = clip(relu(W_int @ h1n + b_int), -20, 20) ----
        if (tid < 320) {
            float a = b_int[tid];
            const uint4* Pv = (const uint4*)(ws + OFF_A4);
#pragma unroll 4
            for (int kb = 0; kb < 32; ++kb) {
                uint4 wv = Pv[kb*320 + tid];
                float4 va = *(const float4*)&h1s[kb*8];
                float4 vb = *(const float4*)&h1s[kb*8 + 4];
                a += bflo(wv.x)*va.x + bfhi(wv.x)*va.y + bflo(wv.y)*va.z + bfhi(wv.y)*va.w
                   + bflo(wv.z)*vb.x + bfhi(wv.z)*vb.y + bflo(wv.w)*vb.z + bfhi(wv.w)*vb.w;
            }
            itf[tid] = fminf(fmaxf(a, 0.f), 20.f);
        }
        __syncthreads();

        // ---- memory ops: save erased slot, write m_t, key norms ----
        const int slot = t & 63;
        if (tid < 32) {
            emer[tid] = em[slot][tid];          // old em slot (em_erased)
            em[slot][tid] = itf[256 + tid];     // em_new: write m_t
            ev[tid] = sigm(itf[288 + tid]);     // e = sigmoid(e_t)
        }
        if (tid >= 32 && tid < 40) {            // key inverse norms (4 em keys, 4 bm keys)
            int r = tid - 32;
            const float* kk = &itf[r*32];       // r<4 -> em keys, r>=4 -> bm keys (itf[128..])
            float s = 0.f;
#pragma unroll
            for (int w2 = 0; w2 < 32; ++w2) { float q = kk[w2]; s += q*q; }
            kinv[r] = 1.f / (sqrtf(s) + 1e-8f);
        }
        __syncthreads();

        // ---- memory row inverse norms (em AFTER slot write; bm OLD) ----
        if (tid < 64) {
            float s = 0.f;
#pragma unroll
            for (int w2 = 0; w2 < 32; ++w2) { float q = em[tid][w2]; s += q*q; }
            minv_em[tid] = 1.f / (sqrtf(s) + 1e-8f);
        } else if (tid < 128) {
            int n = tid - 64; float s = 0.f;
#pragma unroll
            for (int w2 = 0; w2 < 32; ++w2) { float q = bm[n][w2]; s += q*q; }
            minv_bm[n] = 1.f / (sqrtf(s) + 1e-8f);
        }
        __syncthreads();

        // ---- cosine scores (512 dots of length 32) ----
        if (tid < 512) {
            int mm = tid >> 8, r = (tid >> 6) & 3, n = tid & 63;
            const float* kk = &itf[mm*128 + r*32];
            const float (*M)[33] = mm ? bm : em;
            float d = 0.f;
#pragma unroll
            for (int w2 = 0; w2 < 32; ++w2) d += kk[w2] * M[n][w2];
            float val = d * kinv[mm*4 + r] * (mm ? minv_bm[n] : minv_em[n]);
            if (!mm) val /= 0.3f;               // tau for em path
            sc[mm*4 + r][n] = val;
        }
        __syncthreads();

        // ---- softmax over 64 slots: one wave per (mm,r) row ----
        {
            int wave = tid >> 6, lane = tid & 63;
            if (wave < 8) {
                float val = sc[wave][lane];
                float m = val;
                for (int o = 32; o > 0; o >>= 1) m = fmaxf(m, __shfl_xor(m, o));
                float e = __expf(val - m);
                float s = e;
                for (int o = 32; o > 0; o >>= 1) s += __shfl_xor(s, o);
                sc[wave][lane] = e / s;
            }
        }
        __syncthreads();

        // ---- ww (mean of bm weights over r) + weighted reads ----
        if (tid < 64) wwv[tid] = 0.25f * (sc[4][tid] + sc[5][tid] + sc[6][tid] + sc[7][tid]);
        if (tid < 256) {
            int mm = tid >> 7, r = (tid >> 5) & 3, w2 = tid & 31;
            const float (*M)[33] = mm ? bm : em;
            const float* wr = sc[mm*4 + r];
            float a = 0.f;
#pragma unroll 8
            for (int n = 0; n < 64; ++n) a += wr[n] * M[n][w2];
            if (mm) bmrd[r][w2] = a; else emrd[r][w2] = a;
        }
        __syncthreads();

        // ---- mix gate + l_read (threads 0..127) ; bm update (threads 128..767) ----
        if (tid < 128) {
            int r = tid >> 5, w2 = tid & 31;
            float a = bmix[w2];
#pragma unroll
            for (int c = 0; c < 32; ++c) a += wmix_s[w2][c]      * emrd[r][c];
#pragma unroll
            for (int c = 0; c < 32; ++c) a += wmix_s[w2][32 + c] * bmrd[r][c];
            float g  = sigm(a);
            float rd = g * emrd[r][w2] + (1.f - g) * bmrd[r][w2];
            lread[tid] = rd;
            out[outbase + 512 + tid] = rd;
        } else {
            for (int i2 = tid - 128; i2 < 2048; i2 += TPB - 128) {
                int n = i2 >> 5, w2 = i2 & 31;
                bm[n][w2] = bm[n][w2] * (1.f - wwv[n]*ev[w2]) + wwv[n]*emer[w2];
            }
        }
        __syncthreads();
    }
}

extern "C" void kernel_launch(void* const* d_in, const int* in_sizes, int n_in,
                              void* d_out, int out_size, void* d_ws, size_t ws_size,
                              hipStream_t stream)
{
    const float* x    = (const float*)d_in[0];
    const float* h0   = (const float*)d_in[1];
    const float* Wih0 = (const float*)d_in[2];
    const float* Whh0 = (const float*)d_in[3];
    const float* bih0 = (const float*)d_in[4];
    const float* bhh0 = (const float*)d_in[5];
    const float* Wih1 = (const float*)d_in[6];
    const float* Whh1 = (const float*)d_in[7];
    const float* bih1 = (const float*)d_in[8];
    const float* bhh1 = (const float*)d_in[9];
    const float* Wint = (const float*)d_in[10];
    const float* bint = (const float*)d_in[11];
    const float* Wmix = (const float*)d_in[12];
    const float* bmix = (const float*)d_in[13];
    ushort* ws = (ushort*)d_ws;
    float*  out = (float*)d_out;

    if (ws_size < (size_t)WS_USHORTS * sizeof(ushort)) return;  // need ~1.7 MB scratch

    prep_kernel<<<(WS_USHORTS + 255)/256, 256, 0, stream>>>(Wih0, Whh0, Wih1, Whh1, Wint, ws);
    ebm_main<<<64, TPB, 0, stream>>>(x, h0, bih0, bhh0, bih1, bhh1, bint, Wmix, bmix, ws, out);
}